// Round 18
// baseline (7330.936 us; speedup 1.0000x reference)
//
#include <hip/hip_runtime.h>

#define T_STEPS 512
#define E_EDGES 128
#define NN 32
#define HH 256
#define G4 1024   // 4*H
#define NWG 64    // 2 dirs * 32 slots
#define TPB 256

typedef __attribute__((ext_vector_type(8))) short s8v;   // 8 bf16 (4 VGPR)
typedef __attribute__((ext_vector_type(4))) float f4v;   // MFMA acc
typedef unsigned long long u64;

__device__ __forceinline__ float fsig(float x) {
  x = fminf(fmaxf(x, -30.f), 30.f);
  return 1.f / (1.f + __expf(-x));
}
__device__ __forceinline__ float ftanh(float x) {
  float xc = fminf(fmaxf(x, -15.f), 15.f);
  float e = __expf(2.f * xc);
  return (e - 1.f) / (e + 1.f);
}
__device__ __forceinline__ float b2f(short s) {
  return __uint_as_float(((unsigned)(unsigned short)s) << 16);
}
__device__ __forceinline__ unsigned packHL(float f) {
  unsigned fb = __float_as_uint(f);
  unsigned hb = fb & 0xFFFF0000u;
  float lo = f - __uint_as_float(hb);
  return hb | (__float_as_uint(lo) >> 16);
}
// LDS-only barrier (no vmcnt drain) — global stores ride out in the shadow.
__device__ __forceinline__ void bar_lds() {
  asm volatile("s_waitcnt lgkmcnt(0)\n\ts_barrier" ::: "memory");
}

// ---------------- pack f32 -> u32{hi-bf16|lo-bf16} ---------------------
__global__ __launch_bounds__(256) void pack_kernel(const float* __restrict__ in,
    unsigned* __restrict__ out, int n) {
  for (int i = blockIdx.x * 256 + threadIdx.x; i < n; i += gridDim.x * 256)
    out[i] = packHL(in[i]);
}

// ---------------- prep: per-step CSR (edges sorted by dst), both dirs -----
__global__ __launch_bounds__(128) void prep_kernel(const int* __restrict__ src,
    const int* __restrict__ dst, int* __restrict__ eord, int* __restrict__ eoff) {
  __shared__ int de0[E_EDGES], de1[E_EDGES], off0[NN + 1], off1[NN + 1];
  const int t = blockIdx.x, e = threadIdx.x;
  de0[e] = dst[t * E_EDGES + e];
  de1[e] = src[t * E_EDGES + e];
  __syncthreads();
  if (e == 0) {
    int c[NN];
    for (int i = 0; i < NN; ++i) c[i] = 0;
    for (int i = 0; i < E_EDGES; ++i) c[de0[i]]++;
    int s = 0;
    for (int i = 0; i < NN; ++i) { off0[i] = s; s += c[i]; }
    off0[NN] = E_EDGES;
  }
  if (e == 1) {
    int c[NN];
    for (int i = 0; i < NN; ++i) c[i] = 0;
    for (int i = 0; i < E_EDGES; ++i) c[de1[i]]++;
    int s = 0;
    for (int i = 0; i < NN; ++i) { off1[i] = s; s += c[i]; }
    off1[NN] = E_EDGES;
  }
  __syncthreads();
  int d0 = de0[e], r0 = 0, d1 = de1[e], r1 = 0;
  for (int i = 0; i < e; ++i) {
    r0 += (de0[i] == d0);
    r1 += (de1[i] == d1);
  }
  eord[((size_t)0 * T_STEPS + t) * E_EDGES + off0[d0] + r0] = e;
  eord[((size_t)1 * T_STEPS + (T_STEPS - 1 - t)) * E_EDGES + off1[d1] + r1] = e;
  if (e < NN + 1) {
    eoff[((size_t)0 * T_STEPS + t) * (NN + 1) + e] = off0[e];
    eoff[((size_t)1 * T_STEPS + (T_STEPS - 1 - t)) * (NN + 1) + e] = off1[e];
  }
}

// ---------------- gates GEMM via MFMA, PACKED inputs, both dirs --------
// blockIdx.x in [0,16): kb = x&7, reverse = x>=8. One launch covers fwd+bwd.
// Gx[slot][lt][gate][e][jj8] = b[k] + sum_m In[tsrc][e][m] * W[k][m]
template <int M>
__global__ __launch_bounds__(256) void gates_mfma(
    const unsigned* __restrict__ InP, const unsigned* __restrict__ WPF,
    const unsigned* __restrict__ WPB, const float* __restrict__ b2,
    float* __restrict__ GxF, float* __restrict__ GxB, int t0, int Cs) {
  __shared__ short WsT[2][128][72];
  __shared__ short XsT[2][128][72];
  __shared__ float biasL[128];
  const int tid = threadIdx.x;
  const int rev = (blockIdx.x >= 8) ? 1 : 0;
  const int kb = blockIdx.x & 7;
  const unsigned* WP = rev ? WPB : WPF;
  float* Gx = rev ? GxB : GxF;
  const int lt = blockIdx.y;
  const int t = t0 + lt;
  const int tsrc = rev ? (T_STEPS - 1 - t) : t;
  const unsigned* Inb = InP + (size_t)tsrc * E_EDGES * M;

  if (tid < 128) biasL[tid] = b2[rev * G4 + kb * 128 + tid];

  const int lane = tid & 63, wv = tid >> 6;
  const int ll = lane & 15, lh = lane >> 4;
  const int srow = tid >> 1, sh32 = (tid & 1) * 32;

  f4v acc[2][8];
#pragma unroll
  for (int i = 0; i < 2; ++i)
#pragma unroll
    for (int j = 0; j < 8; ++j) acc[i][j] = (f4v){0.f, 0.f, 0.f, 0.f};

  for (int mc = 0; mc < M; mc += 64) {
    __syncthreads();
    {
      const unsigned* wr = WP + (size_t)(kb * 128 + srow) * M + mc + sh32;
      const unsigned* xr = Inb + (size_t)srow * M + mc + sh32;
#pragma unroll
      for (int i = 0; i < 8; ++i) {
        uint4 a = *(const uint4*)(wr + i * 4);
        uint4 x = *(const uint4*)(xr + i * 4);
        int off = sh32 + i * 4;
        *(unsigned*)&WsT[0][srow][off + 0] = (a.x >> 16) | (a.y & 0xFFFF0000u);
        *(unsigned*)&WsT[0][srow][off + 2] = (a.z >> 16) | (a.w & 0xFFFF0000u);
        *(unsigned*)&WsT[1][srow][off + 0] = (a.x & 0xFFFFu) | (a.y << 16);
        *(unsigned*)&WsT[1][srow][off + 2] = (a.z & 0xFFFFu) | (a.w << 16);
        *(unsigned*)&XsT[0][srow][off + 0] = (x.x >> 16) | (x.y & 0xFFFF0000u);
        *(unsigned*)&XsT[0][srow][off + 2] = (x.z >> 16) | (x.w & 0xFFFF0000u);
        *(unsigned*)&XsT[1][srow][off + 0] = (x.x & 0xFFFFu) | (x.y << 16);
        *(unsigned*)&XsT[1][srow][off + 2] = (x.z & 0xFFFFu) | (x.w << 16);
      }
    }
    __syncthreads();
#pragma unroll
    for (int ks = 0; ks < 2; ++ks) {
      const int mo = ks * 32 + lh * 8;
      s8v ah0 = *(const s8v*)&WsT[0][wv * 32 + ll][mo];
      s8v al0 = *(const s8v*)&WsT[1][wv * 32 + ll][mo];
      s8v ah1 = *(const s8v*)&WsT[0][wv * 32 + 16 + ll][mo];
      s8v al1 = *(const s8v*)&WsT[1][wv * 32 + 16 + ll][mo];
#pragma unroll
      for (int et = 0; et < 8; ++et) {
        s8v bh = *(const s8v*)&XsT[0][et * 16 + ll][mo];
        s8v blo = *(const s8v*)&XsT[1][et * 16 + ll][mo];
        acc[0][et] = __builtin_amdgcn_mfma_f32_16x16x32_bf16(ah0, bh, acc[0][et], 0, 0, 0);
        acc[0][et] = __builtin_amdgcn_mfma_f32_16x16x32_bf16(ah0, blo, acc[0][et], 0, 0, 0);
        acc[0][et] = __builtin_amdgcn_mfma_f32_16x16x32_bf16(al0, bh, acc[0][et], 0, 0, 0);
        acc[1][et] = __builtin_amdgcn_mfma_f32_16x16x32_bf16(ah1, bh, acc[1][et], 0, 0, 0);
        acc[1][et] = __builtin_amdgcn_mfma_f32_16x16x32_bf16(ah1, blo, acc[1][et], 0, 0, 0);
        acc[1][et] = __builtin_amdgcn_mfma_f32_16x16x32_bf16(al1, bh, acc[1][et], 0, 0, 0);
      }
    }
  }
#pragma unroll
  for (int kt = 0; kt < 2; ++kt) {
    const int kloc = wv * 32 + kt * 16 + lh * 4;
    const int kg = kb * 128 + kloc;
    const int gate = kg >> 8;
    const int ch = kg & 255;
    const int slot = ch >> 3;
    const int jj0 = ch & 7;
    const float4 bv = *(const float4*)&biasL[kloc];
    float* gb = Gx + ((((size_t)slot * Cs + lt) * 4 + gate) * E_EDGES) * 8 + jj0;
#pragma unroll
    for (int et = 0; et < 8; ++et) {
      int e = et * 16 + ll;
      f4v v = acc[kt][et];
      *(float4*)(gb + (size_t)e * 8) =
          make_float4(v[0] + bv.x, v[1] + bv.y, v[2] + bv.z, v[3] + bv.w);
    }
  }
}

// ---------------- recurrence: R15 structure (verbatim) -----------------
__global__ __launch_bounds__(TPB) void recur_kernel(
    const float* __restrict__ GxF, const float* __restrict__ GxB,
    const float* __restrict__ WhhF, const float* __restrict__ WhhB,
    const int* __restrict__ src, const int* __restrict__ dst,
    const int* __restrict__ eord, const int* __restrict__ eoff,
    u64* hnG, float* cnG, float* outF, unsigned* outP, int packOut,
    int t0, int nsteps) {
  __shared__ short WsB[2][32][33][8];   // Whh slice hi/lo
  __shared__ short hnB[2][32][33][8];   // hn hi/lo
  __shared__ float zF[32][33];
  __shared__ float hE[E_EDGES][8];
  __shared__ float cE[E_EDGES][8];
  __shared__ float cnL[NN][9];
  __shared__ int eordL[E_EDGES];
  __shared__ int eoffL[NN + 1];
  __shared__ int mfmaOK;

  const int tid = threadIdx.x;
  const int wg = blockIdx.x;
  const int dir = wg >> 5;
  const int slot = wg & 31;
  const int j0 = slot * 8;
  const float* Gx = dir ? GxB : GxF;
  const float* Whh = dir ? WhhB : WhhF;
  const int* seA = dir ? dst : src;
  float* cnGd = cnG + (size_t)dir * NN * HH;

  // --- one-time: stage Whh slice as bf16 hi/lo fragments ---
  {
    int gc = tid >> 3;
    int g = gc >> 3, jj2 = gc & 7;
    const float* wr = Whh + ((size_t)(g * HH) + j0 + jj2) * HH;
    int c0 = (tid & 7) * 32;
    for (int kk = 0; kk < 32; ++kk) {
      int k = c0 + kk;
      unsigned p = packHL(wr[k]);
      WsB[0][k >> 3][gc][k & 7] = (short)(p >> 16);
      WsB[1][k >> 3][gc][k & 7] = (short)(p & 0xFFFFu);
    }
  }
  {
    int n = tid >> 3, jj = tid & 7;
    cnL[n][jj] = cnGd[n * HH + j0 + jj];
  }
  // --- one-time: MFMA layout self-test (exact integer check) ---
  if (tid < 64) {
    s8v ta, tb;
    const int rr = tid & 15, kh = (tid >> 4) * 8;
#pragma unroll
    for (int i = 0; i < 8; ++i) {
      int k = kh + i;
      ta[i] = (short)(__float_as_uint((float)((rr + 2 * k) & 7)) >> 16);
      tb[i] = (short)(__float_as_uint((float)(((3 * k + rr) & 7) - 3)) >> 16);
    }
    f4v tacc = {0.f, 0.f, 0.f, 0.f};
    tacc = __builtin_amdgcn_mfma_f32_16x16x32_bf16(ta, tb, tacc, 0, 0, 0);
    bool ok = true;
    const int col = tid & 15, rbase = (tid >> 4) * 4;
#pragma unroll
    for (int g2 = 0; g2 < 4; ++g2) {
      int row = rbase + g2;
      float ex = 0.f;
      for (int k = 0; k < 32; ++k)
        ex += (float)((row + 2 * k) & 7) * (float)(((3 * k + col) & 7) - 3);
      ok &= (tacc[g2] == ex);
    }
    unsigned long long bb = __ballot(ok);
    if (tid == 0) mfmaOK = (bb == 0xFFFFFFFFFFFFFFFFull) ? 1 : 0;
  }
  __syncthreads();
  const bool useMfma = (mfmaOK != 0);

  const int e = tid >> 1, jh = tid & 1;
  const float* gxWG = Gx + (size_t)slot * nsteps * 4096 + (e * 8 + jh * 4);

  for (int rl = 0; rl < nsteps; ++rl) {
    const int r = t0 + rl;
    const int tv = dir ? (T_STEPS - 1 - r) : r;

    // --- P0: issue step-invariant loads (overlap with poll) ---
    const int sec = seA[tv * E_EDGES + e];
    int eoV = 0, eofV = 0;
    if (tid < E_EDGES) eoV = eord[((size_t)dir * T_STEPS + r) * E_EDGES + tid];
    else if (tid < E_EDGES + NN + 1)
      eofV = eoff[((size_t)dir * T_STEPS + r) * (NN + 1) + (tid - E_EDGES)];
    const float* gp = gxWG + (size_t)rl * 4096;
    float4 gxi = *(const float4*)(gp + 0 * 1024);
    float4 gxf = *(const float4*)(gp + 1 * 1024);
    float4 gxg = *(const float4*)(gp + 2 * 1024);
    float4 gxo = *(const float4*)(gp + 3 * 1024);

    // --- P2: poll+stage hn (tagged, PRE-SPLIT) -> bf16 hi/lo LDS ---
    {
      const u64* hnRd = hnG + (size_t)((r & 1) * 2 + dir) * NN * HH;
      const unsigned want = (unsigned)(t0 + rl);
      u64 va[16], vb[16];
#pragma unroll
      for (int p = 0; p < 16; ++p) {
        int idx = tid + 256 * p;
        const u64* ptr = hnRd + (size_t)(idx >> 7) * HH + (idx & 127) * 2;
        va[p] = __hip_atomic_load(ptr, __ATOMIC_RELAXED, __HIP_MEMORY_SCOPE_AGENT);
        vb[p] = __hip_atomic_load(ptr + 1, __ATOMIC_RELAXED, __HIP_MEMORY_SCOPE_AGENT);
      }
      unsigned pend = 0xFFFFu;
      int guard = 0;
      for (;;) {
#pragma unroll
        for (int p = 0; p < 16; ++p) {
          if (pend & (1u << p)) {
            if ((unsigned)(va[p] >> 32) == want && (unsigned)(vb[p] >> 32) == want) {
              pend &= ~(1u << p);
              int idx = tid + 256 * p;
              int n = idx >> 7, c2 = idx & 127;
              unsigned pa = (unsigned)va[p];   // hi16 top | lo16 bottom
              unsigned pb = (unsigned)vb[p];
              unsigned hw = (pa >> 16) | (pb & 0xFFFF0000u);
              unsigned lw = (pa & 0xFFFFu) | (pb << 16);
              int k = c2 * 2;
              ((unsigned*)&hnB[0][k >> 3][n][0])[(k & 7) >> 1] = hw;
              ((unsigned*)&hnB[1][k >> 3][n][0])[(k & 7) >> 1] = lw;
            }
          }
        }
        if (!pend) break;
        if (++guard > (1 << 20)) break;
        __builtin_amdgcn_s_sleep(0);
#pragma unroll
        for (int p = 0; p < 16; ++p) {
          if (pend & (1u << p)) {
            int idx = tid + 256 * p;
            const u64* ptr = hnRd + (size_t)(idx >> 7) * HH + (idx & 127) * 2;
            va[p] = __hip_atomic_load(ptr, __ATOMIC_RELAXED, __HIP_MEMORY_SCOPE_AGENT);
            vb[p] = __hip_atomic_load(ptr + 1, __ATOMIC_RELAXED, __HIP_MEMORY_SCOPE_AGENT);
          }
        }
      }
      if (tid < E_EDGES) eordL[tid] = eoV;
      else if (tid < E_EDGES + NN + 1) eoffL[tid - E_EDGES] = eofV;
    }
    bar_lds();

    // --- P3: z via MFMA — one 16x16 output tile per wave (4 waves) ---
    if (useMfma) {
      const int lane = tid & 63, wv = tid >> 6;
      const int gr = (wv >> 1) * 16;
      const int ncb = (wv & 1) * 16;
      const int ll = lane & 15, lh = lane >> 4;
      f4v ah = {0.f, 0.f, 0.f, 0.f}, bl = {0.f, 0.f, 0.f, 0.f};
#pragma unroll
      for (int kb = 0; kb < 8; ++kb) {
        s8v wh = *(const s8v*)&WsB[0][kb * 4 + lh][gr + ll][0];
        s8v wl = *(const s8v*)&WsB[1][kb * 4 + lh][gr + ll][0];
        s8v hh = *(const s8v*)&hnB[0][kb * 4 + lh][ncb + ll][0];
        s8v hl = *(const s8v*)&hnB[1][kb * 4 + lh][ncb + ll][0];
        ah = __builtin_amdgcn_mfma_f32_16x16x32_bf16(wh, hh, ah, 0, 0, 0);
        bl = __builtin_amdgcn_mfma_f32_16x16x32_bf16(wh, hl, bl, 0, 0, 0);
        bl = __builtin_amdgcn_mfma_f32_16x16x32_bf16(wl, hh, bl, 0, 0, 0);
      }
#pragma unroll
      for (int g2 = 0; g2 < 4; ++g2)
        zF[gr + lh * 4 + g2][ncb + ll] = ah[g2] + bl[g2];
    } else {
      int n = tid & 31, gq = tid >> 5;
      float za[4] = {0.f, 0.f, 0.f, 0.f};
      for (int k = 0; k < 256; ++k) {
        int kb8 = k >> 3, el = k & 7;
        float hv = b2f(hnB[0][kb8][n][el]) + b2f(hnB[1][kb8][n][el]);
#pragma unroll
        for (int q = 0; q < 4; ++q) {
          int gc = gq * 4 + q;
          za[q] += (b2f(WsB[0][kb8][gc][el]) + b2f(WsB[1][kb8][gc][el])) * hv;
        }
      }
#pragma unroll
      for (int q = 0; q < 4; ++q) zF[gq * 4 + q][n] = za[q];
    }
    bar_lds();

    // --- P5: edge phase: gates -> cell -> per-edge h,c; out store ---
    {
      const float gi4[4] = {gxi.x, gxi.y, gxi.z, gxi.w};
      const float gf4[4] = {gxf.x, gxf.y, gxf.z, gxf.w};
      const float gg4[4] = {gxg.x, gxg.y, gxg.z, gxg.w};
      const float go4[4] = {gxo.x, gxo.y, gxo.z, gxo.w};
      float hq[4], cq[4];
#pragma unroll
      for (int u = 0; u < 4; ++u) {
        int jj = jh * 4 + u;
        float gi = gi4[u] + zF[jj][sec];
        float gf = gf4[u] + zF[8 + jj][sec];
        float gv = gg4[u] + zF[16 + jj][sec];
        float go = go4[u] + zF[24 + jj][sec];
        float cv = fsig(gf) * cnL[sec][jj] + fsig(gi) * ftanh(gv);
        float hv = fsig(go) * ftanh(cv);
        hq[u] = hv;
        cq[u] = cv;
      }
      *(float4*)&hE[e][jh * 4] = make_float4(hq[0], hq[1], hq[2], hq[3]);
      *(float4*)&cE[e][jh * 4] = make_float4(cq[0], cq[1], cq[2], cq[3]);
      int tw = dir ? (T_STEPS - 1 - r) : r;
      size_t ob = ((size_t)tw * E_EDGES + e) * 512 + dir * 256 + j0 + jh * 4;
      if (packOut) {
        *(uint4*)(outP + ob) = make_uint4(packHL(hq[0]), packHL(hq[1]),
                                          packHL(hq[2]), packHL(hq[3]));
      } else {
        *(float4*)(outF + ob) = make_float4(hq[0], hq[1], hq[2], hq[3]);
      }
    }
    bar_lds();

    // --- P6: CSR gather -> node means; tagged pre-split u64 store ---
    {
      int n = tid >> 3, jj = tid & 7;
      int o0 = eoffL[n], o1 = eoffL[n + 1];
      float sh = 0.f, sc = 0.f;
      for (int o = o0; o < o1; ++o) {
        int ee = eordL[o];
        sh += hE[ee][jj];
        sc += cE[ee][jj];
      }
      int len = o1 - o0;
      float rdn = (len > 0) ? (1.f / (float)len) : 1.f;
      float hnv = sh * rdn;
      u64 pk = ((u64)(unsigned)(t0 + rl + 1) << 32) | (u64)packHL(hnv);
      u64* hnWr = hnG + (size_t)(((r + 1) & 1) * 2 + dir) * NN * HH +
                  (size_t)n * HH + j0 + jj;
      __hip_atomic_store(hnWr, pk, __ATOMIC_RELAXED, __HIP_MEMORY_SCOPE_AGENT);
      cnL[n][jj] = sc * rdn;
    }
    bar_lds();   // protects eordL/hE/cE (R12 discipline — stability)
  }

  { // persist cell state for next chunk
    int n = tid >> 3, jj = tid & 7;
    cnGd[n * HH + j0 + jj] = cnL[n][jj];
  }
}

// ---------------- host launcher ---------------------------------------
extern "C" void kernel_launch(void* const* d_in, const int* in_sizes, int n_in,
                              void* d_out, int out_size, void* d_ws, size_t ws_size,
                              hipStream_t stream) {
  const float* x = (const float*)d_in[0];
  const float* Wih0 = (const float*)d_in[1];
  const float* Whh0 = (const float*)d_in[2];
  const float* b0 = (const float*)d_in[3];
  const float* Wih1 = (const float*)d_in[4];
  const float* Whh1 = (const float*)d_in[5];
  const float* b1 = (const float*)d_in[6];
  const int* src = (const int*)d_in[7];
  const int* dst = (const int*)d_in[8];
  float* out = (float*)d_out;

  const size_t outElems = (size_t)T_STEPS * E_EDGES * 512;   // out0P (u32)
  const size_t hnW = (size_t)4 * NN * HH;                    // u64 elems
  const size_t eordW = (size_t)2 * T_STEPS * E_EDGES;
  const size_t eoffW = (size_t)2 * T_STEPS * (NN + 1);
  const size_t xPW = (size_t)T_STEPS * E_EDGES * 64;
  const size_t w0PW = (size_t)2 * G4 * 64;
  const size_t w1PW = (size_t)2 * G4 * 512;
  int C = 512;
  while (C >= 1) {
    size_t need = (2 * (size_t)C * G4 * E_EDGES + outElems + 2 * hnW +
                   2 * (size_t)NN * HH + eordW + eoffW +
                   xPW + w0PW + w1PW + 256) * sizeof(float);
    if (need <= ws_size) break;
    C >>= 1;
  }
  if (C < 1) return;

  float* GxF = (float*)d_ws;
  float* GxB = GxF + (size_t)C * G4 * E_EDGES;
  unsigned* out0P = (unsigned*)(GxB + (size_t)C * G4 * E_EDGES);
  u64* hnG = (u64*)(out0P + outElems);
  float* cnG = (float*)(hnG + hnW);
  int* eord = (int*)(cnG + 2 * NN * HH);
  int* eoff = eord + eordW;
  unsigned* xP = (unsigned*)(eoff + eoffW);
  unsigned* w0P = xP + xPW;
  unsigned* w1P = w0P + w0PW;

  prep_kernel<<<dim3(T_STEPS), 128, 0, stream>>>(src, dst, eord, eoff);
  pack_kernel<<<dim3(2048), 256, 0, stream>>>(x, xP, (int)xPW);
  pack_kernel<<<dim3(512), 256, 0, stream>>>(Wih0, w0P, (int)w0PW);
  pack_kernel<<<dim3(2048), 256, 0, stream>>>(Wih1, w1P, (int)w1PW);

  for (int layer = 0; layer < 2; ++layer) {
    const float* Whh = layer ? Whh1 : Whh0;
    const float* bb = layer ? b1 : b0;
    (void)hipMemsetAsync(hnG, 0, hnW * sizeof(u64), stream);
    (void)hipMemsetAsync(cnG, 0, 2 * NN * HH * sizeof(float), stream);
    for (int t0 = 0; t0 < T_STEPS; t0 += C) {
      if (layer == 0) {
        gates_mfma<64><<<dim3(16, C), 256, 0, stream>>>(
            xP, w0P, w0P + (size_t)G4 * 64, bb, GxF, GxB, t0, C);
      } else {
        gates_mfma<512><<<dim3(16, C), 256, 0, stream>>>(
            out0P, w1P, w1P + (size_t)G4 * 512, bb, GxF, GxB, t0, C);
      }
      const float* gxF = GxF; const float* gxB = GxB;
      const float* whF = Whh; const float* whB = Whh + (size_t)G4 * HH;
      const int* psrc = src; const int* pdst = dst;
      const int* peord = eord; const int* peoff = eoff;
      u64* phn = hnG; float* pcn = cnG;
      float* poutF = out; unsigned* poutP = out0P;
      int a_pack = (layer == 0) ? 1 : 0;
      int a_t0 = t0, a_ns = C;
      void* args[16] = {&gxF, &gxB, &whF, &whB, &psrc, &pdst, &peord, &peoff,
                        &phn, &pcn, &poutF, &poutP, &a_pack, &a_t0, &a_ns};
      hipLaunchCooperativeKernel((const void*)recur_kernel, dim3(NWG), dim3(TPB),
                                 args, 0, stream);
    }
  }
}

// Round 20
// 7252.062 us; speedup vs baseline: 1.0109x; 1.0109x over previous
//
#include <hip/hip_runtime.h>

#define T_STEPS 512
#define E_EDGES 128
#define NN 32
#define HH 256
#define G4 1024   // 4*H
#define NWG 64    // 2 dirs * 32 slots
#define TPB 256

typedef __attribute__((ext_vector_type(8))) short s8v;   // 8 bf16 (4 VGPR)
typedef __attribute__((ext_vector_type(4))) float f4v;   // MFMA acc
typedef unsigned long long u64;

__device__ __forceinline__ float fsig(float x) {
  x = fminf(fmaxf(x, -30.f), 30.f);
  return 1.f / (1.f + __expf(-x));
}
__device__ __forceinline__ float ftanh(float x) {
  float xc = fminf(fmaxf(x, -15.f), 15.f);
  float e = __expf(2.f * xc);
  return (e - 1.f) / (e + 1.f);
}
__device__ __forceinline__ float b2f(short s) {
  return __uint_as_float(((unsigned)(unsigned short)s) << 16);
}
__device__ __forceinline__ unsigned packHL(float f) {
  unsigned fb = __float_as_uint(f);
  unsigned hb = fb & 0xFFFF0000u;
  float lo = f - __uint_as_float(hb);
  return hb | (__float_as_uint(lo) >> 16);
}
// LDS-only barrier (no vmcnt drain) — global stores ride out in the shadow.
__device__ __forceinline__ void bar_lds() {
  asm volatile("s_waitcnt lgkmcnt(0)\n\ts_barrier" ::: "memory");
}
// s_sleep needs a constant immediate: backoff ladder with literal tiers.
__device__ __forceinline__ void backoff(int guard) {
  if (guard <= 4) return;            // common case: free spin
  else if (guard <= 8) __builtin_amdgcn_s_sleep(1);
  else if (guard <= 16) __builtin_amdgcn_s_sleep(4);
  else if (guard <= 64) __builtin_amdgcn_s_sleep(16);
  else __builtin_amdgcn_s_sleep(32);
}

// ---------------- pack f32 -> u32{hi-bf16|lo-bf16} ---------------------
__global__ __launch_bounds__(256) void pack_kernel(const float* __restrict__ in,
    unsigned* __restrict__ out, int n) {
  for (int i = blockIdx.x * 256 + threadIdx.x; i < n; i += gridDim.x * 256)
    out[i] = packHL(in[i]);
}

// ---------------- prep: per-step CSR (edges sorted by dst), both dirs -----
__global__ __launch_bounds__(128) void prep_kernel(const int* __restrict__ src,
    const int* __restrict__ dst, int* __restrict__ eord, int* __restrict__ eoff) {
  __shared__ int de0[E_EDGES], de1[E_EDGES], off0[NN + 1], off1[NN + 1];
  const int t = blockIdx.x, e = threadIdx.x;
  de0[e] = dst[t * E_EDGES + e];
  de1[e] = src[t * E_EDGES + e];
  __syncthreads();
  if (e == 0) {
    int c[NN];
    for (int i = 0; i < NN; ++i) c[i] = 0;
    for (int i = 0; i < E_EDGES; ++i) c[de0[i]]++;
    int s = 0;
    for (int i = 0; i < NN; ++i) { off0[i] = s; s += c[i]; }
    off0[NN] = E_EDGES;
  }
  if (e == 1) {
    int c[NN];
    for (int i = 0; i < NN; ++i) c[i] = 0;
    for (int i = 0; i < E_EDGES; ++i) c[de1[i]]++;
    int s = 0;
    for (int i = 0; i < NN; ++i) { off1[i] = s; s += c[i]; }
    off1[NN] = E_EDGES;
  }
  __syncthreads();
  int d0 = de0[e], r0 = 0, d1 = de1[e], r1 = 0;
  for (int i = 0; i < e; ++i) {
    r0 += (de0[i] == d0);
    r1 += (de1[i] == d1);
  }
  eord[((size_t)0 * T_STEPS + t) * E_EDGES + off0[d0] + r0] = e;
  eord[((size_t)1 * T_STEPS + (T_STEPS - 1 - t)) * E_EDGES + off1[d1] + r1] = e;
  if (e < NN + 1) {
    eoff[((size_t)0 * T_STEPS + t) * (NN + 1) + e] = off0[e];
    eoff[((size_t)1 * T_STEPS + (T_STEPS - 1 - t)) * (NN + 1) + e] = off1[e];
  }
}

// ---------------- gates GEMM via MFMA, PACKED inputs -------------------
// In/W are u32{hi16|lo16}; staging is load + shift/mask only.
// Gx[slot][lt][gate][e][jj8] = b[k] + sum_m In[tsrc][e][m] * W[k][m]
template <int M>
__global__ __launch_bounds__(256) void gates_mfma(
    const unsigned* __restrict__ InP, const unsigned* __restrict__ WP,
    const float* __restrict__ b, float* __restrict__ Gx, int reverse, int t0,
    int Cs) {
  __shared__ short WsT[2][128][72];
  __shared__ short XsT[2][128][72];
  __shared__ float biasL[128];
  const int tid = threadIdx.x;
  const int kb = blockIdx.x;
  const int lt = blockIdx.y;
  const int t = t0 + lt;
  const int tsrc = reverse ? (T_STEPS - 1 - t) : t;
  const unsigned* Inb = InP + (size_t)tsrc * E_EDGES * M;

  if (tid < 128) biasL[tid] = b[kb * 128 + tid];

  const int lane = tid & 63, wv = tid >> 6;
  const int ll = lane & 15, lh = lane >> 4;
  const int srow = tid >> 1, sh32 = (tid & 1) * 32;

  f4v acc[2][8];
#pragma unroll
  for (int i = 0; i < 2; ++i)
#pragma unroll
    for (int j = 0; j < 8; ++j) acc[i][j] = (f4v){0.f, 0.f, 0.f, 0.f};

  for (int mc = 0; mc < M; mc += 64) {
    __syncthreads();
    {
      const unsigned* wr = WP + (size_t)(kb * 128 + srow) * M + mc + sh32;
      const unsigned* xr = Inb + (size_t)srow * M + mc + sh32;
#pragma unroll
      for (int i = 0; i < 8; ++i) {
        uint4 a = *(const uint4*)(wr + i * 4);
        uint4 x = *(const uint4*)(xr + i * 4);
        int off = sh32 + i * 4;
        *(unsigned*)&WsT[0][srow][off + 0] = (a.x >> 16) | (a.y & 0xFFFF0000u);
        *(unsigned*)&WsT[0][srow][off + 2] = (a.z >> 16) | (a.w & 0xFFFF0000u);
        *(unsigned*)&WsT[1][srow][off + 0] = (a.x & 0xFFFFu) | (a.y << 16);
        *(unsigned*)&WsT[1][srow][off + 2] = (a.z & 0xFFFFu) | (a.w << 16);
        *(unsigned*)&XsT[0][srow][off + 0] = (x.x >> 16) | (x.y & 0xFFFF0000u);
        *(unsigned*)&XsT[0][srow][off + 2] = (x.z >> 16) | (x.w & 0xFFFF0000u);
        *(unsigned*)&XsT[1][srow][off + 0] = (x.x & 0xFFFFu) | (x.y << 16);
        *(unsigned*)&XsT[1][srow][off + 2] = (x.z & 0xFFFFu) | (x.w << 16);
      }
    }
    __syncthreads();
#pragma unroll
    for (int ks = 0; ks < 2; ++ks) {
      const int mo = ks * 32 + lh * 8;
      s8v ah0 = *(const s8v*)&WsT[0][wv * 32 + ll][mo];
      s8v al0 = *(const s8v*)&WsT[1][wv * 32 + ll][mo];
      s8v ah1 = *(const s8v*)&WsT[0][wv * 32 + 16 + ll][mo];
      s8v al1 = *(const s8v*)&WsT[1][wv * 32 + 16 + ll][mo];
#pragma unroll
      for (int et = 0; et < 8; ++et) {
        s8v bh = *(const s8v*)&XsT[0][et * 16 + ll][mo];
        s8v blo = *(const s8v*)&XsT[1][et * 16 + ll][mo];
        acc[0][et] = __builtin_amdgcn_mfma_f32_16x16x32_bf16(ah0, bh, acc[0][et], 0, 0, 0);
        acc[0][et] = __builtin_amdgcn_mfma_f32_16x16x32_bf16(ah0, blo, acc[0][et], 0, 0, 0);
        acc[0][et] = __builtin_amdgcn_mfma_f32_16x16x32_bf16(al0, bh, acc[0][et], 0, 0, 0);
        acc[1][et] = __builtin_amdgcn_mfma_f32_16x16x32_bf16(ah1, bh, acc[1][et], 0, 0, 0);
        acc[1][et] = __builtin_amdgcn_mfma_f32_16x16x32_bf16(ah1, blo, acc[1][et], 0, 0, 0);
        acc[1][et] = __builtin_amdgcn_mfma_f32_16x16x32_bf16(al1, bh, acc[1][et], 0, 0, 0);
      }
    }
  }
#pragma unroll
  for (int kt = 0; kt < 2; ++kt) {
    const int kloc = wv * 32 + kt * 16 + lh * 4;
    const int kg = kb * 128 + kloc;
    const int gate = kg >> 8;
    const int ch = kg & 255;
    const int slot = ch >> 3;
    const int jj0 = ch & 7;
    const float4 bv = *(const float4*)&biasL[kloc];
    float* gb = Gx + ((((size_t)slot * Cs + lt) * 4 + gate) * E_EDGES) * 8 + jj0;
#pragma unroll
    for (int et = 0; et < 8; ++et) {
      int e = et * 16 + ll;
      f4v v = acc[kt][et];
      *(float4*)(gb + (size_t)e * 8) =
          make_float4(v[0] + bv.x, v[1] + bv.y, v[2] + bv.z, v[3] + bv.w);
    }
  }
}

// ---------------- recurrence: R15 structure + poll backoff -------------
__global__ __launch_bounds__(TPB) void recur_kernel(
    const float* __restrict__ GxF, const float* __restrict__ GxB,
    const float* __restrict__ WhhF, const float* __restrict__ WhhB,
    const int* __restrict__ src, const int* __restrict__ dst,
    const int* __restrict__ eord, const int* __restrict__ eoff,
    u64* hnG, float* cnG, float* outF, unsigned* outP, int packOut,
    int t0, int nsteps) {
  __shared__ short WsB[2][32][33][8];   // Whh slice hi/lo
  __shared__ short hnB[2][32][33][8];   // hn hi/lo
  __shared__ float zF[32][33];
  __shared__ float hE[E_EDGES][8];
  __shared__ float cE[E_EDGES][8];
  __shared__ float cnL[NN][9];
  __shared__ int eordL[E_EDGES];
  __shared__ int eoffL[NN + 1];
  __shared__ int mfmaOK;

  const int tid = threadIdx.x;
  const int wg = blockIdx.x;
  const int dir = wg >> 5;
  const int slot = wg & 31;
  const int j0 = slot * 8;
  const float* Gx = dir ? GxB : GxF;
  const float* Whh = dir ? WhhB : WhhF;
  const int* seA = dir ? dst : src;
  float* cnGd = cnG + (size_t)dir * NN * HH;

  // --- one-time: stage Whh slice as bf16 hi/lo fragments ---
  {
    int gc = tid >> 3;
    int g = gc >> 3, jj2 = gc & 7;
    const float* wr = Whh + ((size_t)(g * HH) + j0 + jj2) * HH;
    int c0 = (tid & 7) * 32;
    for (int kk = 0; kk < 32; ++kk) {
      int k = c0 + kk;
      unsigned p = packHL(wr[k]);
      WsB[0][k >> 3][gc][k & 7] = (short)(p >> 16);
      WsB[1][k >> 3][gc][k & 7] = (short)(p & 0xFFFFu);
    }
  }
  {
    int n = tid >> 3, jj = tid & 7;
    cnL[n][jj] = cnGd[n * HH + j0 + jj];
  }
  // --- one-time: MFMA layout self-test (exact integer check) ---
  if (tid < 64) {
    s8v ta, tb;
    const int rr = tid & 15, kh = (tid >> 4) * 8;
#pragma unroll
    for (int i = 0; i < 8; ++i) {
      int k = kh + i;
      ta[i] = (short)(__float_as_uint((float)((rr + 2 * k) & 7)) >> 16);
      tb[i] = (short)(__float_as_uint((float)(((3 * k + rr) & 7) - 3)) >> 16);
    }
    f4v tacc = {0.f, 0.f, 0.f, 0.f};
    tacc = __builtin_amdgcn_mfma_f32_16x16x32_bf16(ta, tb, tacc, 0, 0, 0);
    bool ok = true;
    const int col = tid & 15, rbase = (tid >> 4) * 4;
#pragma unroll
    for (int g2 = 0; g2 < 4; ++g2) {
      int row = rbase + g2;
      float ex = 0.f;
      for (int k = 0; k < 32; ++k)
        ex += (float)((row + 2 * k) & 7) * (float)(((3 * k + col) & 7) - 3);
      ok &= (tacc[g2] == ex);
    }
    unsigned long long bb = __ballot(ok);
    if (tid == 0) mfmaOK = (bb == 0xFFFFFFFFFFFFFFFFull) ? 1 : 0;
  }
  __syncthreads();
  const bool useMfma = (mfmaOK != 0);

  const int e = tid >> 1, jh = tid & 1;
  const float* gxWG = Gx + (size_t)slot * nsteps * 4096 + (e * 8 + jh * 4);

  for (int rl = 0; rl < nsteps; ++rl) {
    const int r = t0 + rl;
    const int tv = dir ? (T_STEPS - 1 - r) : r;

    // --- P0: issue step-invariant loads (overlap with poll) ---
    const int sec = seA[tv * E_EDGES + e];
    int eoV = 0, eofV = 0;
    if (tid < E_EDGES) eoV = eord[((size_t)dir * T_STEPS + r) * E_EDGES + tid];
    else if (tid < E_EDGES + NN + 1)
      eofV = eoff[((size_t)dir * T_STEPS + r) * (NN + 1) + (tid - E_EDGES)];
    const float* gp = gxWG + (size_t)rl * 4096;
    float4 gxi = *(const float4*)(gp + 0 * 1024);
    float4 gxf = *(const float4*)(gp + 1 * 1024);
    float4 gxg = *(const float4*)(gp + 2 * 1024);
    float4 gxo = *(const float4*)(gp + 3 * 1024);

    // --- P2: poll+stage hn (tagged, PRE-SPLIT) -> bf16 hi/lo LDS ---
    // Exponential backoff (literal-immediate tiers) after 4 failed sweeps:
    // drops LLC load traffic ~50x when a producer lags, preventing the
    // starvation feedback behind rare ~20ms pathological dispatches.
    {
      const u64* hnRd = hnG + (size_t)((r & 1) * 2 + dir) * NN * HH;
      const unsigned want = (unsigned)(t0 + rl);
      u64 va[16], vb[16];
#pragma unroll
      for (int p = 0; p < 16; ++p) {
        int idx = tid + 256 * p;
        const u64* ptr = hnRd + (size_t)(idx >> 7) * HH + (idx & 127) * 2;
        va[p] = __hip_atomic_load(ptr, __ATOMIC_RELAXED, __HIP_MEMORY_SCOPE_AGENT);
        vb[p] = __hip_atomic_load(ptr + 1, __ATOMIC_RELAXED, __HIP_MEMORY_SCOPE_AGENT);
      }
      unsigned pend = 0xFFFFu;
      int guard = 0;
      for (;;) {
#pragma unroll
        for (int p = 0; p < 16; ++p) {
          if (pend & (1u << p)) {
            if ((unsigned)(va[p] >> 32) == want && (unsigned)(vb[p] >> 32) == want) {
              pend &= ~(1u << p);
              int idx = tid + 256 * p;
              int n = idx >> 7, c2 = idx & 127;
              unsigned pa = (unsigned)va[p];   // hi16 top | lo16 bottom
              unsigned pb = (unsigned)vb[p];
              unsigned hw = (pa >> 16) | (pb & 0xFFFF0000u);
              unsigned lw = (pa & 0xFFFFu) | (pb << 16);
              int k = c2 * 2;
              ((unsigned*)&hnB[0][k >> 3][n][0])[(k & 7) >> 1] = hw;
              ((unsigned*)&hnB[1][k >> 3][n][0])[(k & 7) >> 1] = lw;
            }
          }
        }
        if (!pend) break;
        if (++guard > (1 << 20)) break;
        backoff(guard);
#pragma unroll
        for (int p = 0; p < 16; ++p) {
          if (pend & (1u << p)) {
            int idx = tid + 256 * p;
            const u64* ptr = hnRd + (size_t)(idx >> 7) * HH + (idx & 127) * 2;
            va[p] = __hip_atomic_load(ptr, __ATOMIC_RELAXED, __HIP_MEMORY_SCOPE_AGENT);
            vb[p] = __hip_atomic_load(ptr + 1, __ATOMIC_RELAXED, __HIP_MEMORY_SCOPE_AGENT);
          }
        }
      }
      if (tid < E_EDGES) eordL[tid] = eoV;
      else if (tid < E_EDGES + NN + 1) eoffL[tid - E_EDGES] = eofV;
    }
    bar_lds();

    // --- P3: z via MFMA — one 16x16 output tile per wave (4 waves) ---
    if (useMfma) {
      const int lane = tid & 63, wv = tid >> 6;
      const int gr = (wv >> 1) * 16;
      const int ncb = (wv & 1) * 16;
      const int ll = lane & 15, lh = lane >> 4;
      f4v ah = {0.f, 0.f, 0.f, 0.f}, bl = {0.f, 0.f, 0.f, 0.f};
#pragma unroll
      for (int kb = 0; kb < 8; ++kb) {
        s8v wh = *(const s8v*)&WsB[0][kb * 4 + lh][gr + ll][0];
        s8v wl = *(const s8v*)&WsB[1][kb * 4 + lh][gr + ll][0];
        s8v hh = *(const s8v*)&hnB[0][kb * 4 + lh][ncb + ll][0];
        s8v hl = *(const s8v*)&hnB[1][kb * 4 + lh][ncb + ll][0];
        ah = __builtin_amdgcn_mfma_f32_16x16x32_bf16(wh, hh, ah, 0, 0, 0);
        bl = __builtin_amdgcn_mfma_f32_16x16x32_bf16(wh, hl, bl, 0, 0, 0);
        bl = __builtin_amdgcn_mfma_f32_16x16x32_bf16(wl, hh, bl, 0, 0, 0);
      }
#pragma unroll
      for (int g2 = 0; g2 < 4; ++g2)
        zF[gr + lh * 4 + g2][ncb + ll] = ah[g2] + bl[g2];
    } else {
      int n = tid & 31, gq = tid >> 5;
      float za[4] = {0.f, 0.f, 0.f, 0.f};
      for (int k = 0; k < 256; ++k) {
        int kb8 = k >> 3, el = k & 7;
        float hv = b2f(hnB[0][kb8][n][el]) + b2f(hnB[1][kb8][n][el]);
#pragma unroll
        for (int q = 0; q < 4; ++q) {
          int gc = gq * 4 + q;
          za[q] += (b2f(WsB[0][kb8][gc][el]) + b2f(WsB[1][kb8][gc][el])) * hv;
        }
      }
#pragma unroll
      for (int q = 0; q < 4; ++q) zF[gq * 4 + q][n] = za[q];
    }
    bar_lds();

    // --- P5: edge phase: gates -> cell -> per-edge h,c; out store ---
    {
      const float gi4[4] = {gxi.x, gxi.y, gxi.z, gxi.w};
      const float gf4[4] = {gxf.x, gxf.y, gxf.z, gxf.w};
      const float gg4[4] = {gxg.x, gxg.y, gxg.z, gxg.w};
      const float go4[4] = {gxo.x, gxo.y, gxo.z, gxo.w};
      float hq[4], cq[4];
#pragma unroll
      for (int u = 0; u < 4; ++u) {
        int jj = jh * 4 + u;
        float gi = gi4[u] + zF[jj][sec];
        float gf = gf4[u] + zF[8 + jj][sec];
        float gv = gg4[u] + zF[16 + jj][sec];
        float go = go4[u] + zF[24 + jj][sec];
        float cv = fsig(gf) * cnL[sec][jj] + fsig(gi) * ftanh(gv);
        float hv = fsig(go) * ftanh(cv);
        hq[u] = hv;
        cq[u] = cv;
      }
      *(float4*)&hE[e][jh * 4] = make_float4(hq[0], hq[1], hq[2], hq[3]);
      *(float4*)&cE[e][jh * 4] = make_float4(cq[0], cq[1], cq[2], cq[3]);
      int tw = dir ? (T_STEPS - 1 - r) : r;
      size_t ob = ((size_t)tw * E_EDGES + e) * 512 + dir * 256 + j0 + jh * 4;
      if (packOut) {
        *(uint4*)(outP + ob) = make_uint4(packHL(hq[0]), packHL(hq[1]),
                                          packHL(hq[2]), packHL(hq[3]));
      } else {
        *(float4*)(outF + ob) = make_float4(hq[0], hq[1], hq[2], hq[3]);
      }
    }
    bar_lds();

    // --- P6: CSR gather -> node means; tagged pre-split u64 store ---
    {
      int n = tid >> 3, jj = tid & 7;
      int o0 = eoffL[n], o1 = eoffL[n + 1];
      float sh = 0.f, sc = 0.f;
      for (int o = o0; o < o1; ++o) {
        int ee = eordL[o];
        sh += hE[ee][jj];
        sc += cE[ee][jj];
      }
      int len = o1 - o0;
      float rdn = (len > 0) ? (1.f / (float)len) : 1.f;
      float hnv = sh * rdn;
      u64 pk = ((u64)(unsigned)(t0 + rl + 1) << 32) | (u64)packHL(hnv);
      u64* hnWr = hnG + (size_t)(((r + 1) & 1) * 2 + dir) * NN * HH +
                  (size_t)n * HH + j0 + jj;
      __hip_atomic_store(hnWr, pk, __ATOMIC_RELAXED, __HIP_MEMORY_SCOPE_AGENT);
      cnL[n][jj] = sc * rdn;
    }
    bar_lds();   // protects eordL/hE/cE (R12 discipline — stability)
  }

  { // persist cell state for next chunk
    int n = tid >> 3, jj = tid & 7;
    cnGd[n * HH + j0 + jj] = cnL[n][jj];
  }
}

// ---------------- host launcher ---------------------------------------
extern "C" void kernel_launch(void* const* d_in, const int* in_sizes, int n_in,
                              void* d_out, int out_size, void* d_ws, size_t ws_size,
                              hipStream_t stream) {
  const float* x = (const float*)d_in[0];
  const float* Wih0 = (const float*)d_in[1];
  const float* Whh0 = (const float*)d_in[2];
  const float* b0 = (const float*)d_in[3];
  const float* Wih1 = (const float*)d_in[4];
  const float* Whh1 = (const float*)d_in[5];
  const float* b1 = (const float*)d_in[6];
  const int* src = (const int*)d_in[7];
  const int* dst = (const int*)d_in[8];
  float* out = (float*)d_out;

  const size_t outElems = (size_t)T_STEPS * E_EDGES * 512;   // out0P (u32)
  const size_t hnW = (size_t)4 * NN * HH;                    // u64 elems
  const size_t eordW = (size_t)2 * T_STEPS * E_EDGES;
  const size_t eoffW = (size_t)2 * T_STEPS * (NN + 1);
  const size_t xPW = (size_t)T_STEPS * E_EDGES * 64;
  const size_t w0PW = (size_t)2 * G4 * 64;
  const size_t w1PW = (size_t)2 * G4 * 512;
  int C = 512;
  while (C >= 1) {
    size_t need = (2 * (size_t)C * G4 * E_EDGES + outElems + 2 * hnW +
                   2 * (size_t)NN * HH + eordW + eoffW +
                   xPW + w0PW + w1PW + 256) * sizeof(float);
    if (need <= ws_size) break;
    C >>= 1;
  }
  if (C < 1) return;

  float* GxF = (float*)d_ws;
  float* GxB = GxF + (size_t)C * G4 * E_EDGES;
  unsigned* out0P = (unsigned*)(GxB + (size_t)C * G4 * E_EDGES);
  u64* hnG = (u64*)(out0P + outElems);
  float* cnG = (float*)(hnG + hnW);
  int* eord = (int*)(cnG + 2 * NN * HH);
  int* eoff = eord + eordW;
  unsigned* xP = (unsigned*)(eoff + eoffW);
  unsigned* w0P = xP + xPW;
  unsigned* w1P = w0P + w0PW;

  prep_kernel<<<dim3(T_STEPS), 128, 0, stream>>>(src, dst, eord, eoff);
  pack_kernel<<<dim3(2048), 256, 0, stream>>>(x, xP, (int)xPW);
  pack_kernel<<<dim3(512), 256, 0, stream>>>(Wih0, w0P, (int)w0PW);
  pack_kernel<<<dim3(2048), 256, 0, stream>>>(Wih1, w1P, (int)w1PW);

  for (int layer = 0; layer < 2; ++layer) {
    const float* Whh = layer ? Whh1 : Whh0;
    const float* bb = layer ? b1 : b0;
    (void)hipMemsetAsync(hnG, 0, hnW * sizeof(u64), stream);
    (void)hipMemsetAsync(cnG, 0, 2 * NN * HH * sizeof(float), stream);
    for (int t0 = 0; t0 < T_STEPS; t0 += C) {
      if (layer == 0) {
        gates_mfma<64><<<dim3(8, C), 256, 0, stream>>>(xP, w0P, bb, GxF, 0, t0, C);
        gates_mfma<64><<<dim3(8, C), 256, 0, stream>>>(xP, w0P + (size_t)G4 * 64, bb + G4, GxB, 1, t0, C);
      } else {
        gates_mfma<512><<<dim3(8, C), 256, 0, stream>>>(out0P, w1P, bb, GxF, 0, t0, C);
        gates_mfma<512><<<dim3(8, C), 256, 0, stream>>>(out0P, w1P + (size_t)G4 * 512, bb + G4, GxB, 1, t0, C);
      }
      const float* gxF = GxF; const float* gxB = GxB;
      const float* whF = Whh; const float* whB = Whh + (size_t)G4 * HH;
      const int* psrc = src; const int* pdst = dst;
      const int* peord = eord; const int* peoff = eoff;
      u64* phn = hnG; float* pcn = cnG;
      float* poutF = out; unsigned* poutP = out0P;
      int a_pack = (layer == 0) ? 1 : 0;
      int a_t0 = t0, a_ns = C;
      void* args[16] = {&gxF, &gxB, &whF, &whB, &psrc, &pdst, &peord, &peoff,
                        &phn, &pcn, &poutF, &poutP, &a_pack, &a_t0, &a_ns};
      hipLaunchCooperativeKernel((const void*)recur_kernel, dim3(NWG), dim3(TPB),
                                 args, 0, stream);
    }
  }
}